// Round 4
// baseline (235.829 us; speedup 1.0000x reference)
//
#include <hip/hip_runtime.h>
#include <hip/hip_cooperative_groups.h>
#include <hip/hip_fp16.h>
#include <math.h>

namespace cg = cooperative_groups;

#define N      512
#define DIMC   128
#define HEADS  4
#define DH     32
#define INDC   5
#define SCALE  0.1767766952966369f   // 32^-0.5

// ws layout: [rowsKV fp16: 276 rows x 512] [w_outT f32 16384]
//   rowsKV rows: K 0..127, V 128..255, Ak 256..275  (fp16, all i columns)
#define KV_ROWS  276
#define WOUTT_F  (KV_ROWS * N / 2)   // float offset after fp16 rows = 70656

// Single cooperative kernel. Block b owns i-pair (2b, 2b+1).
// Phase A: pre-GEMM for OWN columns (K/V/Ak -> global fp16; q/Aq -> LDS f32),
//          w_out transpose slice, MhS; indicator prefetch overlaps all of it.
// grid.sync()  (device-scope release/acquire -> cross-XCD visibility)
// Phase B: sim -> shuffle-only softmax -> PV   (wave w = head w&3, col w>>2)
// Phase C: fused output projection.
__global__ __launch_bounds__(512) void fused_kernel(
        const float* __restrict__ x,
        const float* __restrict__ ind,
        const float* __restrict__ w_qkv,
        const float* __restrict__ w_ind,
        const float* __restrict__ w_out,
        const float* __restrict__ b_out,
        float* __restrict__ out,
        float* __restrict__ ws) {
    const int i0   = blockIdx.x * 2;
    const int t    = threadIdx.x;
    const int lane = t & 63;
    const int w    = t >> 6;      // 0..7
    const int h    = w & 3;       // head
    const int ii   = w >> 2;      // which i column
    const int i    = i0 + ii;

    __half* rowsKV = (__half*)ws;
    float*  w_outT = ws + WOUTT_F;

    // union: phase A comp_w[40][129] (20.6 KB) / phase B red[8][32][32] (32 KB)
    __shared__ float uni[8 * DH * 32];
    float (*comp_w)[129] = (float (*)[129])uni;
    __shared__ float xcol[2][DIMC];          // 1 KB
    __shared__ float qs[2][DIMC];            // 1 KB
    __shared__ float aqs[2][HEADS * INDC];
    __shared__ float mraw[HEADS * INDC * INDC];
    __shared__ float msS[HEADS * 16];
    __shared__ float attv[2][DIMC];
    __shared__ float outred[8][2][DIMC];     // 8 KB

    // ---- 0) indicator prefetch (HBM-cold) — hides under all of phase A ----
    float4 ic[2][INDC];
#pragma unroll
    for (int s = 0; s < 2; ++s) {
        const int g = lane + 64 * s;
#pragma unroll
        for (int c = 0; c < INDC; ++c)
            ic[s][c] = ((const float4*)(ind + (c * N + i) * N))[g];
    }

    // ---- 1) stage this block's two x columns; raw M products ----
    if (t < 256) {
        const int cc = t & 127, iw = t >> 7;
        xcol[iw][cc] = x[cc * N + i0 + iw];
    } else if (t < 356) {
        const int u = t - 256, hh = u / 25, c = (u / 5) % 5, c2 = u % 5;
        float acc = 0.f;
        for (int d = 0; d < DH; ++d)
            acc = fmaf(w_ind[(hh * DH + d) * INDC + c],
                       w_ind[(DIMC + hh * DH + d) * INDC + c2], acc);
        mraw[u] = acc;
    }

    // ---- 2) composite weights (Aq 0..19, Ak 20..39), padded stride 129 ----
#pragma unroll
    for (int k = 0; k < 10; ++k) {
        const int idx = t + k * 512;            // 0..5119
        const int r = idx >> 7, m = idx & 127;
        const int hh = (r % 20) / INDC, c = (r % 20) % INDC;
        float acc = 0.f;
        if (r < 20) {   // Aq composite: q-rows . W_ind_k
            for (int d = 0; d < DH; ++d)
                acc = fmaf(w_qkv[(hh * DH + d) * DIMC + m],
                           w_ind[(DIMC + hh * DH + d) * INDC + c], acc);
        } else {        // Ak composite: k-rows . W_ind_q
            for (int d = 0; d < DH; ++d)
                acc = fmaf(w_qkv[(DIMC + hh * DH + d) * DIMC + m],
                           w_ind[(hh * DH + d) * INDC + c], acc);
        }
        comp_w[r][m] = acc;
    }
    __syncthreads();

    // ---- 3) 424 dots x 2 columns; route outputs ----
    if (t < 424) {
        float a0 = 0.f, a1 = 0.f;
        if (t < 384) {
            const float* wr = w_qkv + t * DIMC;
#pragma unroll 8
            for (int c = 0; c < DIMC; ++c) {
                const float wv = wr[c];
                a0 = fmaf(wv, xcol[0][c], a0);
                a1 = fmaf(wv, xcol[1][c], a1);
            }
        } else {
            const float* wr = comp_w[t - 384];
#pragma unroll 8
            for (int c = 0; c < DIMC; ++c) {
                const float wv = wr[c];
                a0 = fmaf(wv, xcol[0][c], a0);
                a1 = fmaf(wv, xcol[1][c], a1);
            }
        }
        if (t < DIMC) {                       // q -> LDS f32 (no fp16 trip)
            qs[0][t] = a0; qs[1][t] = a1;
        } else if (t < 384) {                 // K,V -> global fp16 rows 0..255
            const int r = t - DIMC;
            __half2 h2; h2.x = __float2half(a0); h2.y = __float2half(a1);
            *(__half2*)(rowsKV + r * N + i0) = h2;
        } else if (t < 404) {                 // Aq -> LDS f32
            aqs[0][t - 384] = a0; aqs[1][t - 384] = a1;
        } else {                              // Ak -> global fp16 rows 256..275
            const int r = 256 + (t - 404);
            __half2 h2; h2.x = __float2half(a0); h2.y = __float2half(a1);
            *(__half2*)(rowsKV + r * N + i0) = h2;
        }
    } else if (t < 488) {
        // this block's 64-element slice of the w_out transpose
        const int idx = blockIdx.x * 64 + (t - 424);   // 0..16383
        const int c = idx >> 7, o = idx & 127;
        w_outT[c * DIMC + o] = w_out[o * DIMC + c];
    }
    if (t >= 448) {   // symmetrize MhS (64 threads; mraw ready since barrier)
        const int u = t - 448;
        const int hh = u >> 4, idx = u & 15;
        const int PC[10]  = {0, 0, 0, 0, 1, 1, 1, 2, 2, 3};
        const int PCC[10] = {1, 2, 3, 4, 2, 3, 4, 3, 4, 4};
        float s = 0.f;
        if (idx < 5) {
            s = mraw[hh * 25 + idx * 5 + idx];
        } else if (idx < 15) {
            const int c = PC[idx - 5], c2 = PCC[idx - 5];
            s = mraw[hh * 25 + c * 5 + c2] + mraw[hh * 25 + c2 * 5 + c];
        }
        msS[hh * 16 + idx] = s;
    }

    // ---- grid-wide barrier: all K/V/Ak/w_outT columns visible everywhere ----
    __threadfence();
    cg::this_grid().sync();
    __threadfence();

    const float2* k4  = (const float2*)(rowsKV);                 // K rows
    const float2* v4  = (const float2*)(rowsKV + DIMC * N);      // V rows
    const float2* Ak4 = (const float2*)(rowsKV + 2 * DIMC * N);  // Ak rows

    // ---- sim: this wave's (head,i), 4 j per lane per s ----
    float4 sr[2];
    float m = -1e30f;
#pragma unroll
    for (int s = 0; s < 2; ++s) {
        const int g = lane + 64 * s;
        float4 a = {0.f, 0.f, 0.f, 0.f};
#pragma unroll
        for (int d = 0; d < DH; ++d) {
            const float2 raw = k4[(h * DH + d) * 128 + g];
            const float2 fa = __half22float2(*(const __half2*)&raw.x);
            const float2 fb = __half22float2(*(const __half2*)&raw.y);
            const float qv = qs[ii][h * DH + d];
            a.x = fmaf(qv, fa.x, a.x); a.y = fmaf(qv, fa.y, a.y);
            a.z = fmaf(qv, fb.x, a.z); a.w = fmaf(qv, fb.y, a.w);
        }
#pragma unroll
        for (int c = 0; c < INDC; ++c) {
            const float2 raw = Ak4[(h * INDC + c) * 128 + g];
            const float2 fa = __half22float2(*(const __half2*)&raw.x);
            const float2 fb = __half22float2(*(const __half2*)&raw.y);
            const float b0 = aqs[ii][h * INDC + c];
            const float4 v0 = ic[s][c];
            a.x = fmaf(b0 + fa.x, v0.x, a.x); a.y = fmaf(b0 + fa.y, v0.y, a.y);
            a.z = fmaf(b0 + fb.x, v0.z, a.z); a.w = fmaf(b0 + fb.y, v0.w, a.w);
        }
        const int PCf[15]  = {0, 1, 2, 3, 4, 0, 0, 0, 0, 1, 1, 1, 2, 2, 3};
        const int PCCf[15] = {0, 1, 2, 3, 4, 1, 2, 3, 4, 2, 3, 4, 3, 4, 4};
#pragma unroll
        for (int p = 0; p < 15; ++p) {
            const float sv = msS[h * 16 + p];
            const float4 A = ic[s][PCf[p]], B = ic[s][PCCf[p]];
            a.x = fmaf(sv, A.x * B.x, a.x); a.y = fmaf(sv, A.y * B.y, a.y);
            a.z = fmaf(sv, A.z * B.z, a.z); a.w = fmaf(sv, A.w * B.w, a.w);
        }
        sr[s] = make_float4(SCALE * a.x, SCALE * a.y, SCALE * a.z, SCALE * a.w);
        m = fmaxf(m, fmaxf(fmaxf(sr[s].x, sr[s].y), fmaxf(sr[s].z, sr[s].w)));
    }

    // ---- softmax: pure in-wave butterflies ----
#pragma unroll
    for (int off = 1; off < 64; off <<= 1)
        m = fmaxf(m, __shfl_xor(m, off, 64));
    float4 e[2];
    float sum = 0.f;
#pragma unroll
    for (int s = 0; s < 2; ++s) {
        e[s].x = __expf(sr[s].x - m); e[s].y = __expf(sr[s].y - m);
        e[s].z = __expf(sr[s].z - m); e[s].w = __expf(sr[s].w - m);
        sum += (e[s].x + e[s].y) + (e[s].z + e[s].w);
    }
#pragma unroll
    for (int off = 1; off < 64; off <<= 1)
        sum += __shfl_xor(sum, off, 64);
    const float rnorm = 1.f / sum;

    // ---- PV: unnormalized P (registers) x V ----
    float acc[DH];
#pragma unroll
    for (int d = 0; d < DH; ++d) acc[d] = 0.f;
#pragma unroll
    for (int s = 0; s < 2; ++s) {
        const int g = lane + 64 * s;
        const float4 p = e[s];
#pragma unroll
        for (int d = 0; d < DH; ++d) {
            const float2 raw = v4[(h * DH + d) * 128 + g];
            const float2 fa = __half22float2(*(const __half2*)&raw.x);
            const float2 fb = __half22float2(*(const __half2*)&raw.y);
            acc[d] = fmaf(p.x, fa.x, fmaf(p.y, fa.y,
                     fmaf(p.z, fb.x, fmaf(p.w, fb.y, acc[d]))));
        }
    }

    // ---- cross-lane reduce: shfl fold 64->32, then 32x32 XOR transpose ----
    // (comp_w is dead; reuse `uni` as red[8][DH][32])
    __syncthreads();   // ensure no lagging comp_w readers (paranoia; phase A done)
    {
        float (*red)[DH][32] = (float (*)[DH][32])uni;
#pragma unroll
        for (int d = 0; d < DH; ++d)
            acc[d] += __shfl_xor(acc[d], 32, 64);
        const int l5 = lane & 31;
        if (lane < 32) {
#pragma unroll
            for (int dd = 0; dd < DH; ++dd) red[w][dd][l5 ^ dd] = acc[dd];
            float s = 0.f;
#pragma unroll
            for (int kk = 0; kk < 32; ++kk) s += red[w][l5][kk ^ l5];
            attv[ii][h * DH + l5] = s * rnorm;
        }
    }
    __syncthreads();

    // ---- fused output projection: out[:, i0+iw] = w_out @ attv[iw] + b ----
    {
        const int po  = t & 63;         // float2 o-pair index
        const int grp = t >> 6;         // 8 groups of 16 c each
        const float2* wT2 = (const float2*)w_outT;
        float2 a0 = {0.f, 0.f}, a1 = {0.f, 0.f};
#pragma unroll
        for (int c = grp * 16; c < grp * 16 + 16; ++c) {
            const float2 wv = wT2[c * 64 + po];
            const float av0 = attv[0][c], av1 = attv[1][c];
            a0.x = fmaf(wv.x, av0, a0.x); a0.y = fmaf(wv.y, av0, a0.y);
            a1.x = fmaf(wv.x, av1, a1.x); a1.y = fmaf(wv.y, av1, a1.y);
        }
        ((float2*)&outred[grp][0][0])[po] = a0;
        ((float2*)&outred[grp][1][0])[po] = a1;
    }
    __syncthreads();
    if (t < 256) {
        const int o = t & 127, iw = t >> 7;
        float s = 0.f;
#pragma unroll
        for (int g = 0; g < 8; ++g) s += outred[g][iw][o];
        out[o * N + i0 + iw] = s + b_out[o];
    }
}

extern "C" void kernel_launch(void* const* d_in, const int* in_sizes, int n_in,
                              void* d_out, int out_size, void* d_ws, size_t ws_size,
                              hipStream_t stream) {
    const float* x         = (const float*)d_in[0];  // (1,128,512)
    const float* indicator = (const float*)d_in[1];  // (1,5,512,512)
    const float* w_qkv     = (const float*)d_in[2];  // (384,128)
    const float* w_ind     = (const float*)d_in[3];  // (256,5)
    const float* w_out     = (const float*)d_in[4];  // (128,128)
    const float* b_out     = (const float*)d_in[5];  // (128,)
    float* out = (float*)d_out;                      // (1,128,512)
    float* ws  = (float*)d_ws;

    void* args[] = {(void*)&x, (void*)&indicator, (void*)&w_qkv, (void*)&w_ind,
                    (void*)&w_out, (void*)&b_out, (void*)&out, (void*)&ws};
    hipLaunchCooperativeKernel((const void*)fused_kernel,
                               dim3(N / 2), dim3(512), args, 0, stream);
}

// Round 5
// 99.132 us; speedup vs baseline: 2.3789x; 2.3789x over previous
//
#include <hip/hip_runtime.h>
#include <hip/hip_fp16.h>
#include <math.h>

#define N      512
#define DIMC   128
#define HEADS  4
#define DH     32
#define INDC   5
#define SCALE  0.1767766952966369f   // 32^-0.5

// Virtual output rows of the fused pre-GEMM: all are (row_weights) @ x
//   rows [0,384)   : qkv   (q rows 0..127, k 128..255, v 256..383)
//   rows [384,404) : Aq[(h*5+c)]  composite weight  Wq_rows . W_ind_k
//   rows [404,424) : Ak[(h*5+c)]  composite weight  Wk_rows . W_ind_q
// rows are stored FP16 (halves attn's L2-side K/V traffic; error << threshold)
#define QKV_ROWS 384
#define AQ_BASE  384
#define AK_BASE  404
#define TOT_ROWS 424
#define NROW_BLK (TOT_ROWS / 4)   // 106

// ws layout: [rows fp16: TOT_ROWS*N halves][MhS 64 f32][w_outT 16384 f32][scratch]
#define MHS_F    (TOT_ROWS * N / 2)      // float offset after fp16 rows
#define WOUTT_F  (MHS_F + 64)
#define SCRATCH_F (WOUTT_F + DIMC * DIMC)

// ---------------- Kernel 1: fused pre-GEMM + MhS + w_out transpose ----------------
// Also sweeps the 5.24 MB indicator tensor once (L3 warm for attn's cold reads).
__global__ __launch_bounds__(256, 1) void pre_kernel(const float* __restrict__ w_qkv,
                                                     const float* __restrict__ w_ind,
                                                     const float* __restrict__ x,
                                                     const float* __restrict__ w_out,
                                                     const float* __restrict__ ind,
                                                     float* __restrict__ ws) {
    const int bx = blockIdx.x;
    const int t  = threadIdx.x;
    __half* rows  = (__half*)ws;
    float* MhS    = ws + MHS_F;
    float* w_outT = ws + WOUTT_F;

    if (bx == NROW_BLK) {
        if (blockIdx.y != 0) return;
        // --- M[h,c,cc] = sum_d w_ind_q[h,d,c] * w_ind_k[h,d,cc], then symmetrize ---
        __shared__ float mraw[HEADS * INDC * INDC];
        if (t < HEADS * INDC * INDC) {
            const int h = t / 25, c = (t / 5) % 5, cc = t % 5;
            float acc = 0.f;
            for (int d = 0; d < DH; ++d)
                acc = fmaf(w_ind[(h * DH + d) * INDC + c],
                           w_ind[(DIMC + h * DH + d) * INDC + cc], acc);
            mraw[t] = acc;
        }
        __syncthreads();
        if (t < 64) {
            const int h = t >> 4, idx = t & 15;
            const int PC[10]  = {0, 0, 0, 0, 1, 1, 1, 2, 2, 3};
            const int PCC[10] = {1, 2, 3, 4, 2, 3, 4, 3, 4, 4};
            float s = 0.f;
            if (idx < 5) {
                s = mraw[h * 25 + idx * 5 + idx];
            } else if (idx < 15) {
                const int c = PC[idx - 5], cc = PCC[idx - 5];
                s = mraw[h * 25 + c * 5 + cc] + mraw[h * 25 + cc * 5 + c];
            }
            MhS[h * 16 + idx] = s;
        }
        // --- transpose w_out (128x128) so the fused outproj reads coalesced ---
        for (int idx = t; idx < DIMC * DIMC; idx += 256) {
            const int o = idx >> 7, c = idx & 127;
            w_outT[c * DIMC + o] = w_out[idx];
        }
        return;
    }

    // ---- L3 warm: strided sweep of indicator (issued first, overlaps compute) ----
    float wsum = 0.f;
    {
        const int fb = blockIdx.y * NROW_BLK + bx;          // 0..211
        const float4* ip4 = (const float4*)ind;
        const int total = INDC * N * N / 4;                 // 327680 float4
        for (int idx = fb * 256 + t; idx < total; idx += NROW_BLK * 2 * 256) {
            const float4 v = ip4[idx];
            wsum += (v.x + v.y) + (v.z + v.w);
        }
    }

    // --- 4 virtual rows per block, c-major float4 layout in LDS ---
    __shared__ float ws2[4 * DIMC];   // ws2[c*4 + r]
    const int o0 = bx * 4;
    for (int idx = t; idx < 4 * DIMC; idx += 256) {
        const int r = idx & 3, m = idx >> 2;
        const int row = o0 + r;
        float val;
        if (row < QKV_ROWS) {
            val = w_qkv[row * DIMC + m];
        } else if (row < AK_BASE) {              // Aq composite: q-rows . W_ind_k
            const int rr = row - AQ_BASE, h = rr / INDC, c = rr % INDC;
            float acc = 0.f;
            for (int d = 0; d < DH; ++d)
                acc = fmaf(w_qkv[(h * DH + d) * DIMC + m],
                           w_ind[(DIMC + h * DH + d) * INDC + c], acc);
            val = acc;
        } else {                                  // Ak composite: k-rows . W_ind_q
            const int rr = row - AK_BASE, h = rr / INDC, c = rr % INDC;
            float acc = 0.f;
            for (int d = 0; d < DH; ++d)
                acc = fmaf(w_qkv[(DIMC + h * DH + d) * DIMC + m],
                           w_ind[(h * DH + d) * INDC + c], acc);
            val = acc;
        }
        ws2[m * 4 + r] = val;
    }
    __syncthreads();

    const int i = blockIdx.y * 256 + t;   // i-split halves per-block x traffic
    float acc[4] = {0.f, 0.f, 0.f, 0.f};
#pragma unroll 8
    for (int c = 0; c < DIMC; ++c) {
        const float xv = x[c * N + i];
        const float4 wv = *(const float4*)(ws2 + c * 4);
        acc[0] = fmaf(wv.x, xv, acc[0]);
        acc[1] = fmaf(wv.y, xv, acc[1]);
        acc[2] = fmaf(wv.z, xv, acc[2]);
        acc[3] = fmaf(wv.w, xv, acc[3]);
    }
#pragma unroll
    for (int r = 0; r < 4; ++r) rows[(o0 + r) * N + i] = __float2half(acc[r]);

    // keep the warm-sweep loads live (writes harmless scratch if it ever fires)
    if (wsum == -1234.5678f) ws[SCRATCH_F + t] = wsum;
}

// -- Kernel 2: per-i-pair mega kernel, WAVE-PER-HEAD pipeline --
// wave h owns head h end-to-end: sim -> shuffle-only softmax (no barriers,
// no LDS ps round trip) -> PV from registers. Barriers: 3.
// __launch_bounds__(256,1): 4 waves/block = 1 wave/SIMD at grid 256 anyway;
// the relaxed VGPR cap lets the compiler keep far more K/V/Ak loads in flight.
__global__ __launch_bounds__(256, 1) void attn_kernel(const float* __restrict__ ws,
                                                      const float* __restrict__ ind,
                                                      const float* __restrict__ b_out,
                                                      float* __restrict__ out) {
    const int i0   = blockIdx.x * 2;
    const int t    = threadIdx.x;
    const int lane = t & 63;
    const int h    = t >> 6;     // wave index == head

    const __half* rows  = (const __half*)ws;
    const float* MhS    = ws + MHS_F;
    const float* w_outT = ws + WOUTT_F;

    __shared__ float qs[2][DIMC];
    __shared__ float aqs[2][HEADS * INDC];
    __shared__ float msS[HEADS * 16];
    __shared__ float red[HEADS][DH][64];    // 32 KB (reused for both i)
    __shared__ float attv[2][DIMC];
    __shared__ float outred[4][2][DIMC];    // 4 KB

    // ---- issue indicator loads (L3-warm) FIRST, before the staging barrier ----
    // lane g = lane + 64*s owns j-group [4g, 4g+3] of the full 512-j row.
    float4 ic0[2][INDC], ic1[2][INDC];
#pragma unroll
    for (int s = 0; s < 2; ++s) {
        const int g = lane + 64 * s;
#pragma unroll
        for (int c = 0; c < INDC; ++c) {
            ic0[s][c] = ((const float4*)(ind + (c * N + i0) * N))[g];
            ic1[s][c] = ((const float4*)(ind + (c * N + i0 + 1) * N))[g];
        }
    }

    // ---- stage q / aq / MhS into LDS ----
    const __half* q  = rows;
    const __half* Aq = rows + 3 * DIMC * N;
    if (t < DIMC) qs[0][t] = __half2float(q[t * N + i0]);
    else          qs[1][t - DIMC] = __half2float(q[(t - DIMC) * N + i0 + 1]);
    if (t < 2 * HEADS * INDC) {
        const int ii = t / (HEADS * INDC), r = t % (HEADS * INDC);
        aqs[ii][r] = __half2float(Aq[r * N + i0 + ii]);
    } else if (t < 2 * HEADS * INDC + 64) {
        msS[t - 2 * HEADS * INDC] = MhS[t - 2 * HEADS * INDC];
    }
    __syncthreads();

    const float2* k4  = (const float2*)(rows + DIMC * N);           // half4 rows
    const float2* v4  = (const float2*)(rows + 2 * DIMC * N);
    const float2* Ak4 = (const float2*)(rows + (3 * DIMC + HEADS * INDC) * N);

    // ---- sim: wave h, all 512 j of head h (4 j per lane per s) ----
    float4 sr0[2], sr1[2];
    float m0 = -1e30f, m1 = -1e30f;
#pragma unroll
    for (int s = 0; s < 2; ++s) {
        const int g = lane + 64 * s;
        float4 a0 = {0.f, 0.f, 0.f, 0.f}, a1 = {0.f, 0.f, 0.f, 0.f};
#pragma unroll
        for (int d = 0; d < DH; ++d) {
            const float2 raw = k4[(h * DH + d) * 128 + g];
            const float2 fa = __half22float2(*(const __half2*)&raw.x);
            const float2 fb = __half22float2(*(const __half2*)&raw.y);
            const float q0 = qs[0][h * DH + d], q1 = qs[1][h * DH + d];
            a0.x = fmaf(q0, fa.x, a0.x); a0.y = fmaf(q0, fa.y, a0.y);
            a0.z = fmaf(q0, fb.x, a0.z); a0.w = fmaf(q0, fb.y, a0.w);
            a1.x = fmaf(q1, fa.x, a1.x); a1.y = fmaf(q1, fa.y, a1.y);
            a1.z = fmaf(q1, fb.x, a1.z); a1.w = fmaf(q1, fb.y, a1.w);
        }
#pragma unroll
        for (int c = 0; c < INDC; ++c) {
            const float2 raw = Ak4[(h * INDC + c) * 128 + g];
            const float2 fa = __half22float2(*(const __half2*)&raw.x);
            const float2 fb = __half22float2(*(const __half2*)&raw.y);
            const float b0 = aqs[0][h * INDC + c], b1 = aqs[1][h * INDC + c];
            const float4 v0 = ic0[s][c], v1 = ic1[s][c];
            a0.x = fmaf(b0 + fa.x, v0.x, a0.x); a0.y = fmaf(b0 + fa.y, v0.y, a0.y);
            a0.z = fmaf(b0 + fb.x, v0.z, a0.z); a0.w = fmaf(b0 + fb.y, v0.w, a0.w);
            a1.x = fmaf(b1 + fa.x, v1.x, a1.x); a1.y = fmaf(b1 + fa.y, v1.y, a1.y);
            a1.z = fmaf(b1 + fb.x, v1.z, a1.z); a1.w = fmaf(b1 + fb.y, v1.w, a1.w);
        }
        // quadratic term: 15 symmetric (c,cc) pairs, coefficients MhS
        const int PCf[15]  = {0, 1, 2, 3, 4, 0, 0, 0, 0, 1, 1, 1, 2, 2, 3};
        const int PCCf[15] = {0, 1, 2, 3, 4, 1, 2, 3, 4, 2, 3, 4, 3, 4, 4};
#pragma unroll
        for (int p = 0; p < 15; ++p) {
            const float sv = msS[h * 16 + p];
            const float4 A0 = ic0[s][PCf[p]], B0 = ic0[s][PCCf[p]];
            const float4 A1 = ic1[s][PCf[p]], B1 = ic1[s][PCCf[p]];
            a0.x = fmaf(sv, A0.x * B0.x, a0.x); a0.y = fmaf(sv, A0.y * B0.y, a0.y);
            a0.z = fmaf(sv, A0.z * B0.z, a0.z); a0.w = fmaf(sv, A0.w * B0.w, a0.w);
            a1.x = fmaf(sv, A1.x * B1.x, a1.x); a1.y = fmaf(sv, A1.y * B1.y, a1.y);
            a1.z = fmaf(sv, A1.z * B1.z, a1.z); a1.w = fmaf(sv, A1.w * B1.w, a1.w);
        }
        sr0[s] = make_float4(SCALE * a0.x, SCALE * a0.y, SCALE * a0.z, SCALE * a0.w);
        sr1[s] = make_float4(SCALE * a1.x, SCALE * a1.y, SCALE * a1.z, SCALE * a1.w);
        m0 = fmaxf(m0, fmaxf(fmaxf(sr0[s].x, sr0[s].y), fmaxf(sr0[s].z, sr0[s].w)));
        m1 = fmaxf(m1, fmaxf(fmaxf(sr1[s].x, sr1[s].y), fmaxf(sr1[s].z, sr1[s].w)));
    }

    // ---- softmax: pure in-wave butterflies, no barriers ----
#pragma unroll
    for (int off = 1; off < 64; off <<= 1) {
        m0 = fmaxf(m0, __shfl_xor(m0, off, 64));
        m1 = fmaxf(m1, __shfl_xor(m1, off, 64));
    }
    float4 e0[2], e1[2];
    float sum0 = 0.f, sum1 = 0.f;
#pragma unroll
    for (int s = 0; s < 2; ++s) {
        e0[s].x = __expf(sr0[s].x - m0); e0[s].y = __expf(sr0[s].y - m0);
        e0[s].z = __expf(sr0[s].z - m0); e0[s].w = __expf(sr0[s].w - m0);
        e1[s].x = __expf(sr1[s].x - m1); e1[s].y = __expf(sr1[s].y - m1);
        e1[s].z = __expf(sr1[s].z - m1); e1[s].w = __expf(sr1[s].w - m1);
        sum0 += (e0[s].x + e0[s].y) + (e0[s].z + e0[s].w);
        sum1 += (e1[s].x + e1[s].y) + (e1[s].z + e1[s].w);
    }
#pragma unroll
    for (int off = 1; off < 64; off <<= 1) {
        sum0 += __shfl_xor(sum0, off, 64);
        sum1 += __shfl_xor(sum1, off, 64);
    }
    const float r0 = 1.f / sum0, r1 = 1.f / sum1;   // folded into attv store

    // ---- PV: unnormalized P (registers) x V, wave-local ----
    float acc0[DH], acc1[DH];
#pragma unroll
    for (int d = 0; d < DH; ++d) { acc0[d] = 0.f; acc1[d] = 0.f; }
#pragma unroll
    for (int s = 0; s < 2; ++s) {
        const int g = lane + 64 * s;
        const float4 p0 = e0[s], p1 = e1[s];
#pragma unroll
        for (int d = 0; d < DH; ++d) {
            const float2 raw = v4[(h * DH + d) * 128 + g];
            const float2 fa = __half22float2(*(const __half2*)&raw.x);
            const float2 fb = __half22float2(*(const __half2*)&raw.y);
            acc0[d] = fmaf(p0.x, fa.x, fmaf(p0.y, fa.y,
                      fmaf(p0.z, fb.x, fmaf(p0.w, fb.y, acc0[d]))));
            acc1[d] = fmaf(p1.x, fa.x, fmaf(p1.y, fa.y,
                      fmaf(p1.z, fb.x, fmaf(p1.w, fb.y, acc1[d]))));
        }
    }

    // ---- XOR-swizzled in-wave transpose reduce (conflict-free), i0 then i1 ----
    {
        const int d = lane & 31, half = lane >> 5;
#pragma unroll
        for (int dd = 0; dd < DH; ++dd) red[h][dd][lane ^ dd] = acc0[dd];
        float s = 0.f;
#pragma unroll
        for (int kk = 0; kk < 32; ++kk) s += red[h][d][(half * 32 + kk) ^ d];
        s += __shfl_down(s, 32, 64);
        if (lane < 32) attv[0][h * DH + d] = s * r0;
#pragma unroll
        for (int dd = 0; dd < DH; ++dd) red[h][dd][lane ^ dd] = acc1[dd];
        s = 0.f;
#pragma unroll
        for (int kk = 0; kk < 32; ++kk) s += red[h][d][(half * 32 + kk) ^ d];
        s += __shfl_down(s, 32, 64);
        if (lane < 32) attv[1][h * DH + d] = s * r1;
    }
    __syncthreads();

    // ---- fused output projection: out[:, i0+ii] = w_out @ attv[ii] + b ----
    {
        const int po = t & 63;          // float2 o-pair index
        const int quarter = t >> 6;     // 4 quarters of 32 c each
        const float2* wT2 = (const float2*)w_outT;
        float2 a0 = {0.f, 0.f}, a1 = {0.f, 0.f};
#pragma unroll 8
        for (int c = quarter * 32; c < quarter * 32 + 32; ++c) {
            const float2 wv = wT2[c * 64 + po];                // shared load
            const float av0 = attv[0][c], av1 = attv[1][c];
            a0.x = fmaf(wv.x, av0, a0.x); a0.y = fmaf(wv.y, av0, a0.y);
            a1.x = fmaf(wv.x, av1, a1.x); a1.y = fmaf(wv.y, av1, a1.y);
        }
        ((float2*)&outred[quarter][0][0])[po] = a0;
        ((float2*)&outred[quarter][1][0])[po] = a1;
    }
    __syncthreads();
    {
        const int o = t & 127, ii = t >> 7;
        out[o * N + i0 + ii] = ((outred[0][ii][o] + outred[1][ii][o]) +
                                (outred[2][ii][o] + outred[3][ii][o])) + b_out[o];
    }
}

extern "C" void kernel_launch(void* const* d_in, const int* in_sizes, int n_in,
                              void* d_out, int out_size, void* d_ws, size_t ws_size,
                              hipStream_t stream) {
    const float* x         = (const float*)d_in[0];  // (1,128,512)
    const float* indicator = (const float*)d_in[1];  // (1,5,512,512)
    const float* w_qkv     = (const float*)d_in[2];  // (384,128)
    const float* w_ind     = (const float*)d_in[3];  // (256,5)
    const float* w_out     = (const float*)d_in[4];  // (128,128)
    const float* b_out     = (const float*)d_in[5];  // (128,)
    float* out = (float*)d_out;                      // (1,128,512)
    float* ws  = (float*)d_ws;

    pre_kernel<<<dim3(NROW_BLK + 1, 2), 256, 0, stream>>>(w_qkv, w_ind, x, w_out,
                                                          indicator, ws);
    attn_kernel<<<N / 2, 256, 0, stream>>>(ws, indicator, b_out, out);
}

// Round 6
// 98.113 us; speedup vs baseline: 2.4037x; 1.0104x over previous
//
#include <hip/hip_runtime.h>
#include <hip/hip_fp16.h>
#include <math.h>

#define N      512
#define DIMC   128
#define HEADS  4
#define DH     32
#define INDC   5
#define SCALE  0.1767766952966369f   // 32^-0.5

// Virtual output rows of the fused pre-GEMM: all are (row_weights) @ x
//   rows [0,384)   : qkv   (q rows 0..127, k 128..255, v 256..383)
//   rows [384,404) : Aq[(h*5+c)]  composite weight  Wq_rows . W_ind_k
//   rows [404,424) : Ak[(h*5+c)]  composite weight  Wk_rows . W_ind_q
// rows are stored FP16 (halves attn's L2-side K/V traffic; error << threshold)
#define QKV_ROWS 384
#define AQ_BASE  384
#define AK_BASE  404
#define TOT_ROWS 424
#define NROW_BLK (TOT_ROWS / 4)   // 106

// ws layout: [rows fp16: TOT_ROWS*N halves][MhS 64 f32][w_outT 16384 f32]
#define MHS_F    (TOT_ROWS * N / 2)      // float offset after fp16 rows
#define WOUTT_F  (MHS_F + 64)

// ---------------- Kernel 1: fused pre-GEMM + MhS + w_out transpose ----------------
__global__ __launch_bounds__(256) void pre_kernel(const float* __restrict__ w_qkv,
                                                  const float* __restrict__ w_ind,
                                                  const float* __restrict__ x,
                                                  const float* __restrict__ w_out,
                                                  float* __restrict__ ws) {
    const int bx = blockIdx.x;
    const int t  = threadIdx.x;
    __half* rows  = (__half*)ws;
    float* MhS    = ws + MHS_F;
    float* w_outT = ws + WOUTT_F;

    if (bx == NROW_BLK) {
        if (blockIdx.y != 0) return;
        // --- M[h,c,cc] = sum_d w_ind_q[h,d,c] * w_ind_k[h,d,cc], then symmetrize ---
        __shared__ float mraw[HEADS * INDC * INDC];
        if (t < HEADS * INDC * INDC) {
            const int h = t / 25, c = (t / 5) % 5, cc = t % 5;
            float acc = 0.f;
            for (int d = 0; d < DH; ++d)
                acc = fmaf(w_ind[(h * DH + d) * INDC + c],
                           w_ind[(DIMC + h * DH + d) * INDC + cc], acc);
            mraw[t] = acc;
        }
        __syncthreads();
        if (t < 64) {
            const int h = t >> 4, idx = t & 15;
            const int PC[10]  = {0, 0, 0, 0, 1, 1, 1, 2, 2, 3};
            const int PCC[10] = {1, 2, 3, 4, 2, 3, 4, 3, 4, 4};
            float s = 0.f;
            if (idx < 5) {
                s = mraw[h * 25 + idx * 5 + idx];
            } else if (idx < 15) {
                const int c = PC[idx - 5], cc = PCC[idx - 5];
                s = mraw[h * 25 + c * 5 + cc] + mraw[h * 25 + cc * 5 + c];
            }
            MhS[h * 16 + idx] = s;
        }
        // --- transpose w_out (128x128) so the fused outproj reads coalesced ---
        for (int idx = t; idx < DIMC * DIMC; idx += 256) {
            const int o = idx >> 7, c = idx & 127;
            w_outT[c * DIMC + o] = w_out[idx];
        }
        return;
    }

    // --- 4 virtual rows per block, c-major float4 layout in LDS ---
    __shared__ float ws2[4 * DIMC];   // ws2[c*4 + r]
    const int o0 = bx * 4;
    for (int idx = t; idx < 4 * DIMC; idx += 256) {
        const int r = idx & 3, m = idx >> 2;
        const int row = o0 + r;
        float val;
        if (row < QKV_ROWS) {
            val = w_qkv[row * DIMC + m];
        } else if (row < AK_BASE) {              // Aq composite: q-rows . W_ind_k
            const int rr = row - AQ_BASE, h = rr / INDC, c = rr % INDC;
            float acc = 0.f;
            for (int d = 0; d < DH; ++d)
                acc = fmaf(w_qkv[(h * DH + d) * DIMC + m],
                           w_ind[(DIMC + h * DH + d) * INDC + c], acc);
            val = acc;
        } else {                                  // Ak composite: k-rows . W_ind_q
            const int rr = row - AK_BASE, h = rr / INDC, c = rr % INDC;
            float acc = 0.f;
            for (int d = 0; d < DH; ++d)
                acc = fmaf(w_qkv[(DIMC + h * DH + d) * DIMC + m],
                           w_ind[(h * DH + d) * INDC + c], acc);
            val = acc;
        }
        ws2[m * 4 + r] = val;
    }
    __syncthreads();

    const int i = blockIdx.y * 256 + t;   // i-split halves per-block x traffic
    float acc[4] = {0.f, 0.f, 0.f, 0.f};
#pragma unroll 8
    for (int c = 0; c < DIMC; ++c) {
        const float xv = x[c * N + i];
        const float4 wv = *(const float4*)(ws2 + c * 4);
        acc[0] = fmaf(wv.x, xv, acc[0]);
        acc[1] = fmaf(wv.y, xv, acc[1]);
        acc[2] = fmaf(wv.z, xv, acc[2]);
        acc[3] = fmaf(wv.w, xv, acc[3]);
    }
#pragma unroll
    for (int r = 0; r < 4; ++r) rows[(o0 + r) * N + i] = __float2half(acc[r]);
}

// -- Kernel 2: per-i-pair mega kernel, WAVE-PER-HEAD pipeline --
// wave h owns head h end-to-end: sim -> shuffle-only softmax (no barriers,
// no LDS ps round trip) -> PV from registers. Barriers: 3.
__global__ __launch_bounds__(256) void attn_kernel(const float* __restrict__ ws,
                                                   const float* __restrict__ ind,
                                                   const float* __restrict__ b_out,
                                                   float* __restrict__ out) {
    const int i0   = blockIdx.x * 2;
    const int t    = threadIdx.x;
    const int lane = t & 63;
    const int h    = t >> 6;     // wave index == head

    const __half* rows  = (const __half*)ws;
    const float* MhS    = ws + MHS_F;
    const float* w_outT = ws + WOUTT_F;

    const __half* q  = rows;
    const __half* Aq = rows + 3 * DIMC * N;

    __shared__ float qs[2][DIMC];
    __shared__ float aqs[2][HEADS * INDC];
    __shared__ float msS[HEADS * 16];
    __shared__ float red[HEADS][DH][64];    // 32 KB (reused for both i)
    __shared__ float attv[2][DIMC];
    __shared__ float outred[4][2][DIMC];    // 4 KB

    // ---- issue indicator loads (cold HBM) FIRST, before the staging barrier ----
    // lane g = lane + 64*s owns j-group [4g, 4g+3] of the full 512-j row.
    float4 ic0[2][INDC], ic1[2][INDC];
#pragma unroll
    for (int s = 0; s < 2; ++s) {
        const int g = lane + 64 * s;
#pragma unroll
        for (int c = 0; c < INDC; ++c) {
            ic0[s][c] = ((const float4*)(ind + (c * N + i0) * N))[g];
            ic1[s][c] = ((const float4*)(ind + (c * N + i0 + 1) * N))[g];
        }
    }

    // ---- stage q / aq / MhS into LDS ----
    if (t < DIMC) qs[0][t] = __half2float(q[t * N + i0]);
    else          qs[1][t - DIMC] = __half2float(q[(t - DIMC) * N + i0 + 1]);
    if (t < 2 * HEADS * INDC) {
        const int ii = t / (HEADS * INDC), r = t % (HEADS * INDC);
        aqs[ii][r] = __half2float(Aq[r * N + i0 + ii]);
    } else if (t < 2 * HEADS * INDC + 64) {
        msS[t - 2 * HEADS * INDC] = MhS[t - 2 * HEADS * INDC];
    }
    __syncthreads();

    const float2* k4  = (const float2*)(rows + DIMC * N);           // half4 rows
    const float2* v4  = (const float2*)(rows + 2 * DIMC * N);
    const float2* Ak4 = (const float2*)(rows + (3 * DIMC + HEADS * INDC) * N);

    // ---- sim: wave h, all 512 j of head h (4 j per lane per s) ----
    float4 sr0[2], sr1[2];
    float m0 = -1e30f, m1 = -1e30f;
#pragma unroll
    for (int s = 0; s < 2; ++s) {
        const int g = lane + 64 * s;
        float4 a0 = {0.f, 0.f, 0.f, 0.f}, a1 = {0.f, 0.f, 0.f, 0.f};
#pragma unroll
        for (int d = 0; d < DH; ++d) {
            const float2 raw = k4[(h * DH + d) * 128 + g];
            const float2 fa = __half22float2(*(const __half2*)&raw.x);
            const float2 fb = __half22float2(*(const __half2*)&raw.y);
            const float q0 = qs[0][h * DH + d], q1 = qs[1][h * DH + d];
            a0.x = fmaf(q0, fa.x, a0.x); a0.y = fmaf(q0, fa.y, a0.y);
            a0.z = fmaf(q0, fb.x, a0.z); a0.w = fmaf(q0, fb.y, a0.w);
            a1.x = fmaf(q1, fa.x, a1.x); a1.y = fmaf(q1, fa.y, a1.y);
            a1.z = fmaf(q1, fb.x, a1.z); a1.w = fmaf(q1, fb.y, a1.w);
        }
#pragma unroll
        for (int c = 0; c < INDC; ++c) {
            const float2 raw = Ak4[(h * INDC + c) * 128 + g];
            const float2 fa = __half22float2(*(const __half2*)&raw.x);
            const float2 fb = __half22float2(*(const __half2*)&raw.y);
            const float b0 = aqs[0][h * INDC + c], b1 = aqs[1][h * INDC + c];
            const float4 v0 = ic0[s][c], v1 = ic1[s][c];
            a0.x = fmaf(b0 + fa.x, v0.x, a0.x); a0.y = fmaf(b0 + fa.y, v0.y, a0.y);
            a0.z = fmaf(b0 + fb.x, v0.z, a0.z); a0.w = fmaf(b0 + fb.y, v0.w, a0.w);
            a1.x = fmaf(b1 + fa.x, v1.x, a1.x); a1.y = fmaf(b1 + fa.y, v1.y, a1.y);
            a1.z = fmaf(b1 + fb.x, v1.z, a1.z); a1.w = fmaf(b1 + fb.y, v1.w, a1.w);
        }
        // quadratic term: 15 symmetric (c,cc) pairs, coefficients MhS
        const int PCf[15]  = {0, 1, 2, 3, 4, 0, 0, 0, 0, 1, 1, 1, 2, 2, 3};
        const int PCCf[15] = {0, 1, 2, 3, 4, 1, 2, 3, 4, 2, 3, 4, 3, 4, 4};
#pragma unroll
        for (int p = 0; p < 15; ++p) {
            const float sv = msS[h * 16 + p];
            const float4 A0 = ic0[s][PCf[p]], B0 = ic0[s][PCCf[p]];
            const float4 A1 = ic1[s][PCf[p]], B1 = ic1[s][PCCf[p]];
            a0.x = fmaf(sv, A0.x * B0.x, a0.x); a0.y = fmaf(sv, A0.y * B0.y, a0.y);
            a0.z = fmaf(sv, A0.z * B0.z, a0.z); a0.w = fmaf(sv, A0.w * B0.w, a0.w);
            a1.x = fmaf(sv, A1.x * B1.x, a1.x); a1.y = fmaf(sv, A1.y * B1.y, a1.y);
            a1.z = fmaf(sv, A1.z * B1.z, a1.z); a1.w = fmaf(sv, A1.w * B1.w, a1.w);
        }
        sr0[s] = make_float4(SCALE * a0.x, SCALE * a0.y, SCALE * a0.z, SCALE * a0.w);
        sr1[s] = make_float4(SCALE * a1.x, SCALE * a1.y, SCALE * a1.z, SCALE * a1.w);
        m0 = fmaxf(m0, fmaxf(fmaxf(sr0[s].x, sr0[s].y), fmaxf(sr0[s].z, sr0[s].w)));
        m1 = fmaxf(m1, fmaxf(fmaxf(sr1[s].x, sr1[s].y), fmaxf(sr1[s].z, sr1[s].w)));
    }

    // ---- softmax: pure in-wave butterflies, no barriers ----
#pragma unroll
    for (int off = 1; off < 64; off <<= 1) {
        m0 = fmaxf(m0, __shfl_xor(m0, off, 64));
        m1 = fmaxf(m1, __shfl_xor(m1, off, 64));
    }
    float4 e0[2], e1[2];
    float sum0 = 0.f, sum1 = 0.f;
#pragma unroll
    for (int s = 0; s < 2; ++s) {
        e0[s].x = __expf(sr0[s].x - m0); e0[s].y = __expf(sr0[s].y - m0);
        e0[s].z = __expf(sr0[s].z - m0); e0[s].w = __expf(sr0[s].w - m0);
        e1[s].x = __expf(sr1[s].x - m1); e1[s].y = __expf(sr1[s].y - m1);
        e1[s].z = __expf(sr1[s].z - m1); e1[s].w = __expf(sr1[s].w - m1);
        sum0 += (e0[s].x + e0[s].y) + (e0[s].z + e0[s].w);
        sum1 += (e1[s].x + e1[s].y) + (e1[s].z + e1[s].w);
    }
#pragma unroll
    for (int off = 1; off < 64; off <<= 1) {
        sum0 += __shfl_xor(sum0, off, 64);
        sum1 += __shfl_xor(sum1, off, 64);
    }
    const float r0 = 1.f / sum0, r1 = 1.f / sum1;   // folded into attv store

    // ---- PV: unnormalized P (registers) x V, wave-local ----
    float acc0[DH], acc1[DH];
#pragma unroll
    for (int d = 0; d < DH; ++d) { acc0[d] = 0.f; acc1[d] = 0.f; }
#pragma unroll
    for (int s = 0; s < 2; ++s) {
        const int g = lane + 64 * s;
        const float4 p0 = e0[s], p1 = e1[s];
#pragma unroll
        for (int d = 0; d < DH; ++d) {
            const float2 raw = v4[(h * DH + d) * 128 + g];
            const float2 fa = __half22float2(*(const __half2*)&raw.x);
            const float2 fb = __half22float2(*(const __half2*)&raw.y);
            acc0[d] = fmaf(p0.x, fa.x, fmaf(p0.y, fa.y,
                      fmaf(p0.z, fb.x, fmaf(p0.w, fb.y, acc0[d]))));
            acc1[d] = fmaf(p1.x, fa.x, fmaf(p1.y, fa.y,
                      fmaf(p1.z, fb.x, fmaf(p1.w, fb.y, acc1[d]))));
        }
    }

    // ---- XOR-swizzled in-wave transpose reduce (conflict-free), i0 then i1 ----
    {
        const int d = lane & 31, half = lane >> 5;
#pragma unroll
        for (int dd = 0; dd < DH; ++dd) red[h][dd][lane ^ dd] = acc0[dd];
        float s = 0.f;
#pragma unroll
        for (int kk = 0; kk < 32; ++kk) s += red[h][d][(half * 32 + kk) ^ d];
        s += __shfl_down(s, 32, 64);
        if (lane < 32) attv[0][h * DH + d] = s * r0;
#pragma unroll
        for (int dd = 0; dd < DH; ++dd) red[h][dd][lane ^ dd] = acc1[dd];
        s = 0.f;
#pragma unroll
        for (int kk = 0; kk < 32; ++kk) s += red[h][d][(half * 32 + kk) ^ d];
        s += __shfl_down(s, 32, 64);
        if (lane < 32) attv[1][h * DH + d] = s * r1;
    }
    __syncthreads();

    // ---- fused output projection: out[:, i0+ii] = w_out @ attv[ii] + b ----
    {
        const int po = t & 63;          // float2 o-pair index
        const int quarter = t >> 6;     // 4 quarters of 32 c each
        const float2* wT2 = (const float2*)w_outT;
        float2 a0 = {0.f, 0.f}, a1 = {0.f, 0.f};
#pragma unroll 8
        for (int c = quarter * 32; c < quarter * 32 + 32; ++c) {
            const float2 wv = wT2[c * 64 + po];                // shared load
            const float av0 = attv[0][c], av1 = attv[1][c];
            a0.x = fmaf(wv.x, av0, a0.x); a0.y = fmaf(wv.y, av0, a0.y);
            a1.x = fmaf(wv.x, av1, a1.x); a1.y = fmaf(wv.y, av1, a1.y);
        }
        ((float2*)&outred[quarter][0][0])[po] = a0;
        ((float2*)&outred[quarter][1][0])[po] = a1;
    }
    __syncthreads();
    {
        const int o = t & 127, ii = t >> 7;
        out[o * N + i0 + ii] = ((outred[0][ii][o] + outred[1][ii][o]) +
                                (outred[2][ii][o] + outred[3][ii][o])) + b_out[o];
    }
}

extern "C" void kernel_launch(void* const* d_in, const int* in_sizes, int n_in,
                              void* d_out, int out_size, void* d_ws, size_t ws_size,
                              hipStream_t stream) {
    const float* x         = (const float*)d_in[0];  // (1,128,512)
    const float* indicator = (const float*)d_in[1];  // (1,5,512,512)
    const float* w_qkv     = (const float*)d_in[2];  // (384,128)
    const float* w_ind     = (const float*)d_in[3];  // (256,5)
    const float* w_out     = (const float*)d_in[4];  // (128,128)
    const float* b_out     = (const float*)d_in[5];  // (128,)
    float* out = (float*)d_out;                      // (1,128,512)
    float* ws  = (float*)d_ws;

    pre_kernel<<<dim3(NROW_BLK + 1, 2), 256, 0, stream>>>(w_qkv, w_ind, x, w_out, ws);
    attn_kernel<<<N / 2, 256, 0, stream>>>(ws, indicator, b_out, out);
}